// Round 6
// baseline (170.735 us; speedup 1.0000x reference)
//
#include <hip/hip_runtime.h>

#define BB 16
#define CC 2
#define TT 1000
#define FF 257
#define NBC (BB * CC)                               // 32
#define LCH 25                                      // timesteps per slab
#define KCH 40                                      // slabs per bc (25*40=1000)
#define SLAB_F2 (LCH * FF)                          // 6425 float2 = 51400 B
#define RES_ELEMS ((size_t)BB * CC * TT * FF * 2)   // 16,448,000
#define NTHR 320                                    // 5 waves

// Slab (bc,k) of input is ONE contiguous 51.4 KB region: stage it to LDS with
// stride-1 coalesced loads, then thread f scans chain f from LDS.
// PASS2=false: write chunk summary e[bc][k][f] only.
// PASS2=true : Horner-combine e[bc][0..k-1][f] -> exact init state, rescan,
//              write y (full-row coalesced) and s_last (k==KCH-1).
template <bool PASS2>
__global__ __launch_bounds__(NTHR) void fnorm_pass(
    const float* __restrict__ input,
    const float* __restrict__ weights,
    const float* __restrict__ bias,
    const float* __restrict__ alpha,
    const float* __restrict__ s1,
    float* __restrict__ e,          // [NBC][KCH][FF] in d_ws
    float* __restrict__ out)
{
    __shared__ float2 xs[SLAB_F2];

    const int bid = blockIdx.x;
    const int bc  = bid / KCH;
    const int k   = bid % KCH;
    const int tid = threadIdx.x;
    const int c   = bc % CC;

    // stage slab (contiguous) -> LDS, 512 B per wave per iteration
    const float2* __restrict__ slab =
        (const float2*)input + ((size_t)bc * TT + (size_t)k * LCH) * FF;
    for (int i = tid; i < SLAB_F2; i += NTHR)
        xs[i] = slab[i];

    // per-chain params + init state (no LDS dependency -> overlaps staging)
    float av = 0.f, om = 1.f, w = 0.f, bi = 0.f, S = 0.f;
    const int f = tid;
    if (f < FF) {
        const int cf = c * FF + f;
        av = 1.0f / (1.0f + __expf(-alpha[cf]));
        om = 1.0f - av;
        if (PASS2) {
            w  = weights[cf];
            bi = bias[cf];
            // p = om^LCH  (LCH = 25 = 16+8+1)
            float p2 = om * om, p4 = p2 * p2, p8 = p4 * p4, p16 = p8 * p8;
            float p = p16 * p8 * om;
            // Horner over predecessor chunk summaries (uniform trip count k)
            S = s1[bc * FF + f];
            const float* __restrict__ erow = e + (size_t)bc * KCH * FF + f;
            for (int kk = 0; kk < k; ++kk)
                S = fmaf(S, p, erow[(size_t)kk * FF]);
        }
    }

    __syncthreads();

    if (f < FF) {
        if (PASS2) {
            float2* __restrict__ out2 =
                (float2*)out + ((size_t)bc * TT + (size_t)k * LCH) * FF + f;
            float s = S;
            #pragma unroll
            for (int t = 0; t < LCH; ++t) {
                float2 v = xs[t * FF + f];
                float d2 = fmaf(v.x, v.x, v.y * v.y);
                s = fmaf(d2, av, s * om);
                float inv = __frsqrt_rn(s + 1e-16f) * w;
                float2 y;
                y.x = fmaf(v.x, inv, bi);
                y.y = fmaf(v.y, inv, bi);
                out2[(size_t)t * FF] = y;
            }
            if (k == KCH - 1)
                out[RES_ELEMS + (size_t)bc * FF + f] = s;   // s_last
        } else {
            float s = 0.0f;
            #pragma unroll
            for (int t = 0; t < LCH; ++t) {
                float2 v = xs[t * FF + f];
                float d2 = fmaf(v.x, v.x, v.y * v.y);
                s = fmaf(d2, av, s * om);
            }
            e[((size_t)bc * KCH + k) * FF + f] = s;   // chunk-local end value
        }
    }
}

extern "C" void kernel_launch(void* const* d_in, const int* in_sizes, int n_in,
                              void* d_out, int out_size, void* d_ws, size_t ws_size,
                              hipStream_t stream) {
    const float* input   = (const float*)d_in[0];
    const float* weights = (const float*)d_in[1];
    const float* bias    = (const float*)d_in[2];
    const float* alpha   = (const float*)d_in[3];
    const float* s1      = (const float*)d_in[4];
    float* out = (float*)d_out;
    float* e   = (float*)d_ws;          // needs NBC*KCH*FF*4 = 1.26 MB

    dim3 block(NTHR);
    dim3 grid(NBC * KCH);               // 1280 blocks
    hipLaunchKernelGGL(fnorm_pass<false>, grid, block, 0, stream,
                       input, weights, bias, alpha, s1, e, out);
    hipLaunchKernelGGL(fnorm_pass<true>, grid, block, 0, stream,
                       input, weights, bias, alpha, s1, e, out);
}